// Round 1
// baseline (120.874 us; speedup 1.0000x reference)
//
#include <hip/hip_runtime.h>

// RGate: apply Rx(angle[i]) to every qubit of a 22-qubit statevector.
// Gate on qubit i pairs indices at stride 2^(21-i); all gates commute.
// 3 fused passes: bits 0-10 (kernel A), 11-15 (B1), 16-21 (B2), in-place on d_out.

constexpr int NTOT = 1 << 22;   // 2^22 amplitudes

__device__ __forceinline__ void rotg(float& ar, float& ai, float& br, float& bi,
                                     float c, float s) {
    // a' = c*a - i*s*b ; b' = c*b - i*s*a
    float t0 = ar, t1 = ai, t2 = br, t3 = bi;
    ar = fmaf(c, t0,  s * t3);
    ai = fmaf(c, t1, -s * t2);
    br = fmaf(c, t2,  s * t1);
    bi = fmaf(c, t3, -s * t0);
}

// cs table: cs_c[k]/cs_s[k] for stride-bit k (angle index 21-k)
__device__ __forceinline__ void build_cs(const float* __restrict__ ang,
                                         float* cs_c, float* cs_s, int t) {
    if (t < 22) {
        float a = 0.5f * ang[21 - t];
        cs_c[t] = cosf(a);
        cs_s[t] = sinf(a);
    }
}

// ---------------- Kernel A: bits 0..10, contiguous 2048-element blocks ----
__global__ __launch_bounds__(256) void rgate_low(const float* __restrict__ xr,
                                                 const float* __restrict__ xi,
                                                 const float* __restrict__ ang,
                                                 float* __restrict__ out) {
    __shared__ float sr[2304];   // 2048 + pad (slot = idx + (idx>>3))
    __shared__ float si[2304];
    __shared__ float cs_c[22], cs_s[22];
    const int t  = threadIdx.x;
    const int g0 = blockIdx.x << 11;

    build_cs(ang, cs_c, cs_s, t);

    // load 8 consecutive complex per thread (coalesced float4)
    float ar[8], ai[8];
    {
        const float4* xr4 = (const float4*)(xr + g0) + 2 * t;
        const float4* xi4 = (const float4*)(xi + g0) + 2 * t;
        float4 a0 = xr4[0], a1 = xr4[1];
        float4 b0 = xi4[0], b1 = xi4[1];
        ar[0]=a0.x; ar[1]=a0.y; ar[2]=a0.z; ar[3]=a0.w;
        ar[4]=a1.x; ar[5]=a1.y; ar[6]=a1.z; ar[7]=a1.w;
        ai[0]=b0.x; ai[1]=b0.y; ai[2]=b0.z; ai[3]=b0.w;
        ai[4]=b1.x; ai[5]=b1.y; ai[6]=b1.z; ai[7]=b1.w;
    }
    __syncthreads();   // cs ready

    // gates k=0,1,2 (element stride 1,2,4 == j stride)
    #pragma unroll
    for (int k = 0; k < 3; ++k) {
        const int m = 1 << k;
        const float c = cs_c[k], s = cs_s[k];
        #pragma unroll
        for (int j = 0; j < 8; ++j)
            if (!(j & m)) rotg(ar[j], ai[j], ar[j|m], ai[j|m], c, s);
    }
    // spill to padded LDS: slot(8t+j) = 9t+j
    #pragma unroll
    for (int j = 0; j < 8; ++j) { sr[9*t + j] = ar[j]; si[9*t + j] = ai[j]; }
    __syncthreads();

    // stage 2: idx = 64*hi + 8*j + lo  -> gates k=3,4,5 (stride 8,16,32)
    {
        const int base = 72 * (t >> 3) + (t & 7);
        #pragma unroll
        for (int j = 0; j < 8; ++j) { ar[j] = sr[base + 9*j]; ai[j] = si[base + 9*j]; }
        #pragma unroll
        for (int k = 3; k < 6; ++k) {
            const int m = 1 << (k - 3);
            const float c = cs_c[k], s = cs_s[k];
            #pragma unroll
            for (int j = 0; j < 8; ++j)
                if (!(j & m)) rotg(ar[j], ai[j], ar[j|m], ai[j|m], c, s);
        }
        #pragma unroll
        for (int j = 0; j < 8; ++j) { sr[base + 9*j] = ar[j]; si[base + 9*j] = ai[j]; }
    }
    __syncthreads();

    // stage 3: idx = 512*hi2 + 64*j + lo2 -> gates k=6,7,8 (stride 64,128,256)
    {
        const int lo2  = t & 63;
        const int base = 576 * (t >> 6) + lo2 + (lo2 >> 3);
        #pragma unroll
        for (int j = 0; j < 8; ++j) { ar[j] = sr[base + 72*j]; ai[j] = si[base + 72*j]; }
        #pragma unroll
        for (int k = 6; k < 9; ++k) {
            const int m = 1 << (k - 6);
            const float c = cs_c[k], s = cs_s[k];
            #pragma unroll
            for (int j = 0; j < 8; ++j)
                if (!(j & m)) rotg(ar[j], ai[j], ar[j|m], ai[j|m], c, s);
        }
        #pragma unroll
        for (int j = 0; j < 8; ++j) { sr[base + 72*j] = ar[j]; si[base + 72*j] = ai[j]; }
    }
    __syncthreads();

    // stage 4: idx = 512*j + lo3 -> gates k=9,10 (stride 512,1024), then store
    #pragma unroll
    for (int grp = 0; grp < 2; ++grp) {
        const int lo3  = t + (grp << 8);
        const int base = lo3 + (lo3 >> 3);
        float br_[4], bi_[4];
        #pragma unroll
        for (int j = 0; j < 4; ++j) { br_[j] = sr[base + 576*j]; bi_[j] = si[base + 576*j]; }
        {   // k=9: m=1 ; k=10: m=2
            const float c9 = cs_c[9], s9 = cs_s[9];
            rotg(br_[0], bi_[0], br_[1], bi_[1], c9, s9);
            rotg(br_[2], bi_[2], br_[3], bi_[3], c9, s9);
            const float c10 = cs_c[10], s10 = cs_s[10];
            rotg(br_[0], bi_[0], br_[2], bi_[2], c10, s10);
            rotg(br_[1], bi_[1], br_[3], bi_[3], c10, s10);
        }
        #pragma unroll
        for (int j = 0; j < 4; ++j) {
            out[g0 + lo3 + 512*j]        = br_[j];
            out[NTOT + g0 + lo3 + 512*j] = bi_[j];
        }
    }
}

// ---------------- Kernel B1: bits 11..15 (h stride 2048), tile 32h x 64l ---
__global__ __launch_bounds__(256) void rgate_mid(const float* __restrict__ ang,
                                                 float* __restrict__ out) {
    __shared__ float sr[2048], si[2048];
    __shared__ float cs_c[22], cs_s[22];
    const int t    = threadIdx.x;
    const int bid  = blockIdx.x;
    const int base = ((bid >> 5) << 16) + ((bid & 31) << 6);  // u*65536 + l0
    float* outr = out;
    float* outi = out + NTOT;

    build_cs(ang, cs_c, cs_s, t);

    #pragma unroll
    for (int e = 0; e < 8; ++e) {
        const int f = e * 256 + t;                       // f = h*64 + lo
        const int g = base + ((f >> 6) << 11) + (f & 63);
        sr[f] = outr[g]; si[f] = outi[g];
    }
    __syncthreads();

    #pragma unroll
    for (int gg = 0; gg < 5; ++gg) {
        const int   sh = 1 << gg;
        const float c  = cs_c[11 + gg], s = cs_s[11 + gg];
        #pragma unroll
        for (int e = 0; e < 4; ++e) {
            const int p  = e * 256 + t;          // pair id: hp*64 + lo
            const int lo = p & 63, hp = p >> 6;
            const int hl = hp & (sh - 1);
            const int ha = ((hp - hl) << 1) + hl;
            const int sa = (ha << 6) + lo;
            const int sb = sa + (sh << 6);
            rotg(sr[sa], si[sa], sr[sb], si[sb], c, s);
        }
        __syncthreads();
    }

    #pragma unroll
    for (int e = 0; e < 8; ++e) {
        const int f = e * 256 + t;
        const int g = base + ((f >> 6) << 11) + (f & 63);
        outr[g] = sr[f]; outi[g] = si[f];
    }
}

// ---------------- Kernel B2: bits 16..21 (h stride 65536), tile 64h x 32l --
__global__ __launch_bounds__(256) void rgate_high(const float* __restrict__ ang,
                                                  float* __restrict__ out) {
    __shared__ float sr[2048], si[2048];
    __shared__ float cs_c[22], cs_s[22];
    const int t    = threadIdx.x;
    const int l0   = blockIdx.x << 5;
    float* outr = out;
    float* outi = out + NTOT;

    build_cs(ang, cs_c, cs_s, t);

    #pragma unroll
    for (int e = 0; e < 8; ++e) {
        const int f = e * 256 + t;                       // f = h*32 + lo
        const int g = ((f >> 5) << 16) + l0 + (f & 31);
        sr[f] = outr[g]; si[f] = outi[g];
    }
    __syncthreads();

    #pragma unroll
    for (int gg = 0; gg < 6; ++gg) {
        const int   sh = 1 << gg;
        const float c  = cs_c[16 + gg], s = cs_s[16 + gg];
        #pragma unroll
        for (int e = 0; e < 4; ++e) {
            const int p  = e * 256 + t;          // pair id: hp*32 + lo
            const int lo = p & 31, hp = p >> 5;
            const int hl = hp & (sh - 1);
            const int ha = ((hp - hl) << 1) + hl;
            const int sa = (ha << 5) + lo;
            const int sb = sa + (sh << 5);
            rotg(sr[sa], si[sa], sr[sb], si[sb], c, s);
        }
        __syncthreads();
    }

    #pragma unroll
    for (int e = 0; e < 8; ++e) {
        const int f = e * 256 + t;
        const int g = ((f >> 5) << 16) + l0 + (f & 31);
        outr[g] = sr[f]; outi[g] = si[f];
    }
}

extern "C" void kernel_launch(void* const* d_in, const int* in_sizes, int n_in,
                              void* d_out, int out_size, void* d_ws, size_t ws_size,
                              hipStream_t stream) {
    const float* xr  = (const float*)d_in[0];
    const float* xi  = (const float*)d_in[1];
    const float* ang = (const float*)d_in[2];
    float* out = (float*)d_out;

    // Pass 1: bits 0-10, d_in -> d_out (fully overwrites d_out)
    rgate_low<<<2048, 256, 0, stream>>>(xr, xi, ang, out);
    // Pass 2: bits 11-15, in-place on d_out
    rgate_mid<<<2048, 256, 0, stream>>>(ang, out);
    // Pass 3: bits 16-21, in-place on d_out
    rgate_high<<<2048, 256, 0, stream>>>(ang, out);
}

// Round 2
// 112.965 us; speedup vs baseline: 1.0700x; 1.0700x over previous
//
#include <hip/hip_runtime.h>

// RGate: apply Rx(angle[i]) to every qubit of a 22-qubit statevector.
// Gate on qubit i pairs indices at stride 2^(21-i); all gates commute.
// 3 passes: bits 0-11 (A, 2 LDS re-tiles), 12-16 (B1, 1 re-tile),
// 17-21 (B2, 1 re-tile). Register butterflies; LDS only for re-tiling,
// packed float2 (re,im) -> ds_*_b64.

constexpr int NTOT = 1 << 22;   // 2^22 amplitudes

__device__ __forceinline__ void rotg(float& ar, float& ai, float& br, float& bi,
                                     float c, float s) {
    // a' = c*a - i*s*b ; b' = c*b - i*s*a
    float t0 = ar, t1 = ai, t2 = br, t3 = bi;
    ar = fmaf(c, t0,  s * t3);
    ai = fmaf(c, t1, -s * t2);
    br = fmaf(c, t2,  s * t1);
    bi = fmaf(c, t3, -s * t0);
}

// cs table: cs_c[k]/cs_s[k] for stride-bit k (angle index 21-k)
__device__ __forceinline__ void build_cs(const float* __restrict__ ang,
                                         float* cs_c, float* cs_s, int t) {
    if (t < 22) {
        float a = 0.5f * ang[21 - t];
        cs_c[t] = cosf(a);
        cs_s[t] = sinf(a);
    }
}

__device__ __forceinline__ int padslot(int i) { return i + (i >> 4) + (i >> 8); }

// ---------------- Kernel A: bits 0..11, tile = 4096 contiguous -------------
// Block 256 threads, 16 complex/thread. Arrangements:
//  A1 (load):  idx = t + 256*j        -> reg bits {8..11}, gates k=8..11
//  A2:         idx = (t&15)+16*j+256*(t>>4) -> reg {4..7}, gates k=4..7
//  A3 (store): idx = j + 16*t         -> reg {0..3}, gates k=0..3, float4 out
__global__ __launch_bounds__(256, 4) void rgate_low(const float* __restrict__ xr,
                                                    const float* __restrict__ xi,
                                                    const float* __restrict__ ang,
                                                    float* __restrict__ out) {
    __shared__ float2 sv[4368];          // 4096 + pad
    __shared__ float cs_c[22], cs_s[22];
    const int t  = threadIdx.x;
    const int g0 = blockIdx.x << 12;

    build_cs(ang, cs_c, cs_s, t);

    float ar[16], ai[16];
    const float* xrp = xr + g0 + t;
    const float* xip = xi + g0 + t;
    #pragma unroll
    for (int j = 0; j < 16; ++j) {
        ar[j] = xrp[j << 8];
        ai[j] = xip[j << 8];
    }
    __syncthreads();   // cs ready

    // gates k=8..11 on register index
    #pragma unroll
    for (int b = 0; b < 4; ++b) {
        const int m = 1 << b;
        const float c = cs_c[8 + b], s = cs_s[8 + b];
        #pragma unroll
        for (int j = 0; j < 16; ++j)
            if (!(j & m)) rotg(ar[j], ai[j], ar[j | m], ai[j | m], c, s);
    }
    #pragma unroll
    for (int j = 0; j < 16; ++j)
        sv[padslot(t + (j << 8))] = make_float2(ar[j], ai[j]);
    __syncthreads();

    // A2: reg bits {4..7}
    {
        const int base2 = (t & 15) + ((t >> 4) << 8);
        #pragma unroll
        for (int j = 0; j < 16; ++j) {
            float2 v = sv[padslot(base2 + (j << 4))];
            ar[j] = v.x; ai[j] = v.y;
        }
        #pragma unroll
        for (int b = 0; b < 4; ++b) {
            const int m = 1 << b;
            const float c = cs_c[4 + b], s = cs_s[4 + b];
            #pragma unroll
            for (int j = 0; j < 16; ++j)
                if (!(j & m)) rotg(ar[j], ai[j], ar[j | m], ai[j | m], c, s);
        }
        #pragma unroll
        for (int j = 0; j < 16; ++j)
            sv[padslot(base2 + (j << 4))] = make_float2(ar[j], ai[j]);
    }
    __syncthreads();

    // A3: reg bits {0..3}, then coalesced float4 stores
    {
        const int base3 = t << 4;
        #pragma unroll
        for (int j = 0; j < 16; ++j) {
            float2 v = sv[padslot(base3 + j)];
            ar[j] = v.x; ai[j] = v.y;
        }
        #pragma unroll
        for (int b = 0; b < 4; ++b) {
            const int m = 1 << b;
            const float c = cs_c[b], s = cs_s[b];
            #pragma unroll
            for (int j = 0; j < 16; ++j)
                if (!(j & m)) rotg(ar[j], ai[j], ar[j | m], ai[j | m], c, s);
        }
        float4* orp = (float4*)(out + g0 + base3);
        float4* oip = (float4*)(out + NTOT + g0 + base3);
        #pragma unroll
        for (int q = 0; q < 4; ++q) {
            orp[q] = make_float4(ar[4*q], ar[4*q+1], ar[4*q+2], ar[4*q+3]);
            oip[q] = make_float4(ai[4*q], ai[4*q+1], ai[4*q+2], ai[4*q+3]);
        }
    }
}

// ---------------- Kernel B1: bits 12..16 (h stride 4096) -------------------
// idx = U*131072 + h*4096 + l ; tile = all 32 h x 64 l. Block 256, 8/thread.
// lane = l (conflict-free LDS), w = t>>6.
//  arr1: h = j | (w<<3)            -> gates k=12,13,14
//  arr2: h = ((j&3)<<3)|(w<<1)|(j>>2) -> gates k=15,16
__global__ __launch_bounds__(256) void rgate_mid(const float* __restrict__ ang,
                                                 float* __restrict__ out) {
    __shared__ float2 sv[2048];
    __shared__ float cs_c[22], cs_s[22];
    const int t    = threadIdx.x;
    const int lane = t & 63, w = t >> 6;
    const int bid  = blockIdx.x;
    const int base = ((bid >> 6) << 17) + ((bid & 63) << 6) + lane;
    float* outr = out;
    float* outi = out + NTOT;

    build_cs(ang, cs_c, cs_s, t);

    float ar[8], ai[8];
    #pragma unroll
    for (int j = 0; j < 8; ++j) {
        const int g = base + ((j | (w << 3)) << 12);
        ar[j] = outr[g]; ai[j] = outi[g];
    }
    __syncthreads();   // cs ready

    #pragma unroll
    for (int b = 0; b < 3; ++b) {
        const int m = 1 << b;
        const float c = cs_c[12 + b], s = cs_s[12 + b];
        #pragma unroll
        for (int j = 0; j < 8; ++j)
            if (!(j & m)) rotg(ar[j], ai[j], ar[j | m], ai[j | m], c, s);
    }
    #pragma unroll
    for (int j = 0; j < 8; ++j)
        sv[((j | (w << 3)) << 6) + lane] = make_float2(ar[j], ai[j]);
    __syncthreads();

    #pragma unroll
    for (int j = 0; j < 8; ++j) {
        const int h = ((j & 3) << 3) | (w << 1) | (j >> 2);
        float2 v = sv[(h << 6) + lane];
        ar[j] = v.x; ai[j] = v.y;
    }
    #pragma unroll
    for (int b = 0; b < 2; ++b) {
        const int m = 1 << b;
        const float c = cs_c[15 + b], s = cs_s[15 + b];
        #pragma unroll
        for (int j = 0; j < 8; ++j)
            if (!(j & m)) rotg(ar[j], ai[j], ar[j | m], ai[j | m], c, s);
    }
    #pragma unroll
    for (int j = 0; j < 8; ++j) {
        const int h = ((j & 3) << 3) | (w << 1) | (j >> 2);
        const int g = base + (h << 12);
        outr[g] = ar[j]; outi[g] = ai[j];
    }
}

// ---------------- Kernel B2: bits 17..21 (u stride 131072) -----------------
// idx = u*131072 + m ; tile = all 32 u x 64 m. Block 256, 8/thread.
//  arr1: u = j | (w<<3)            -> gates k=17,18,19
//  arr2: u = ((j&3)<<3)|(w<<1)|(j>>2) -> gates k=20,21
__global__ __launch_bounds__(256) void rgate_high(const float* __restrict__ ang,
                                                  float* __restrict__ out) {
    __shared__ float2 sv[2048];
    __shared__ float cs_c[22], cs_s[22];
    const int t    = threadIdx.x;
    const int lane = t & 63, w = t >> 6;
    const int base = (blockIdx.x << 6) + lane;
    float* outr = out;
    float* outi = out + NTOT;

    build_cs(ang, cs_c, cs_s, t);

    float ar[8], ai[8];
    #pragma unroll
    for (int j = 0; j < 8; ++j) {
        const int g = ((j | (w << 3)) << 17) + base;
        ar[j] = outr[g]; ai[j] = outi[g];
    }
    __syncthreads();   // cs ready

    #pragma unroll
    for (int b = 0; b < 3; ++b) {
        const int m = 1 << b;
        const float c = cs_c[17 + b], s = cs_s[17 + b];
        #pragma unroll
        for (int j = 0; j < 8; ++j)
            if (!(j & m)) rotg(ar[j], ai[j], ar[j | m], ai[j | m], c, s);
    }
    #pragma unroll
    for (int j = 0; j < 8; ++j)
        sv[((j | (w << 3)) << 6) + lane] = make_float2(ar[j], ai[j]);
    __syncthreads();

    #pragma unroll
    for (int j = 0; j < 8; ++j) {
        const int u = ((j & 3) << 3) | (w << 1) | (j >> 2);
        float2 v = sv[(u << 6) + lane];
        ar[j] = v.x; ai[j] = v.y;
    }
    #pragma unroll
    for (int b = 0; b < 2; ++b) {
        const int m = 1 << b;
        const float c = cs_c[20 + b], s = cs_s[20 + b];
        #pragma unroll
        for (int j = 0; j < 8; ++j)
            if (!(j & m)) rotg(ar[j], ai[j], ar[j | m], ai[j | m], c, s);
    }
    #pragma unroll
    for (int j = 0; j < 8; ++j) {
        const int u = ((j & 3) << 3) | (w << 1) | (j >> 2);
        const int g = (u << 17) + base;
        outr[g] = ar[j]; outi[g] = ai[j];
    }
}

extern "C" void kernel_launch(void* const* d_in, const int* in_sizes, int n_in,
                              void* d_out, int out_size, void* d_ws, size_t ws_size,
                              hipStream_t stream) {
    const float* xr  = (const float*)d_in[0];
    const float* xi  = (const float*)d_in[1];
    const float* ang = (const float*)d_in[2];
    float* out = (float*)d_out;

    // Pass 1: bits 0-11, d_in -> d_out (fully overwrites d_out)
    rgate_low<<<1024, 256, 0, stream>>>(xr, xi, ang, out);
    // Pass 2: bits 12-16, in-place on d_out
    rgate_mid<<<2048, 256, 0, stream>>>(ang, out);
    // Pass 3: bits 17-21, in-place on d_out
    rgate_high<<<2048, 256, 0, stream>>>(ang, out);
}